// Round 15
// baseline (1155.167 us; speedup 1.0000x reference)
//
#include <hip/hip_runtime.h>
#include <math.h>

#define BATCH 256
#define DIN 512
#define DFEAT 512
#define HSZ 512
#define VOCAB 32000
#define EMB 64
#define SLEN 16
#define NTILE 500          // VOCAB / 64 col-tiles (argmax view)
#define MARGIN 0.0625f

typedef __attribute__((ext_vector_type(8))) short bf16x8;
typedef __attribute__((ext_vector_type(4))) float f32x4;

__device__ inline unsigned bf16_rne(float x) {
    union { float f; unsigned u; } u; u.f = x;
    unsigned r = u.u + 0x7fff + ((u.u >> 16) & 1);
    return r >> 16;
}

// ---------- fp32 SMEM GEMM (prologue): C = A @ W^T (+bias) ----------
template<int BM, int BN, int BK, int TM, int TN>
__global__ __launch_bounds__(256) void gemm_atb(
    const float* __restrict__ A,
    const float* __restrict__ W,
    const float* __restrict__ bias,
    float* __restrict__ C, long long ldc,
    int M, int N, int K)
{
    __shared__ float As[BK][BM + 4];
    __shared__ float Bs[BK][BN + 4];
    constexpr int THREADS = (BM / TM) * (BN / TN);
    const int tid = threadIdx.x;
    const int tx = tid % (BN / TN);
    const int ty = tid / (BN / TN);
    const int row0 = blockIdx.y * BM;
    const int col0 = blockIdx.x * BN;
    float acc[TM][TN] = {};
    for (int k0 = 0; k0 < K; k0 += BK) {
        for (int i = tid; i < BM * BK; i += THREADS) {
            int m = i / BK, k = i % BK;
            As[k][m] = A[(long long)(row0 + m) * K + k0 + k];
        }
        for (int i = tid; i < BN * BK; i += THREADS) {
            int n = i / BK, k = i % BK;
            Bs[k][n] = W[(long long)(col0 + n) * K + k0 + k];
        }
        __syncthreads();
        #pragma unroll
        for (int kk = 0; kk < BK; ++kk) {
            float a[TM], b[TN];
            #pragma unroll
            for (int i = 0; i < TM; ++i) a[i] = As[kk][ty * TM + i];
            #pragma unroll
            for (int j = 0; j < TN; ++j) b[j] = Bs[kk][tx * TN + j];
            #pragma unroll
            for (int i = 0; i < TM; ++i)
                #pragma unroll
                for (int j = 0; j < TN; ++j)
                    acc[i][j] = fmaf(a[i], b[j], acc[i][j]);
        }
        __syncthreads();
    }
    #pragma unroll
    for (int i = 0; i < TM; ++i) {
        long long m = row0 + ty * TM + i;
        float* crow = C + m * ldc;
        #pragma unroll
        for (int j = 0; j < TN; ++j) {
            int n = col0 + tx * TN + j;
            float v = acc[i][j];
            if (bias) v += bias[n];
            crow[n] = v;
        }
    }
}

// ---------- fused prologue: Wb cast, Wcat2/bcat2 build, counter reset ----------
__global__ void prep_kernel(const float* __restrict__ out_W, ushort* __restrict__ Wb,
                            const float* __restrict__ W_ih, const float* __restrict__ W_hh,
                            const float* __restrict__ b_ih, const float* __restrict__ b_hh,
                            float* __restrict__ Wcat2, float* __restrict__ bcat2,
                            int* __restrict__ done)
{
    const int stride = gridDim.x * 256;
    const int t0 = blockIdx.x * 256 + threadIdx.x;
    for (int i = t0; i < VOCAB * HSZ / 4; i += stride) {
        const float4 v = ((const float4*)out_W)[i];
        ushort4 o;
        o.x = (ushort)bf16_rne(v.x); o.y = (ushort)bf16_rne(v.y);
        o.z = (ushort)bf16_rne(v.z); o.w = (ushort)bf16_rne(v.w);
        ((ushort4*)Wb)[i] = o;
    }
    for (long long i = t0; i < 2048LL * 576; i += stride) {
        int g = (int)(i / 576), k = (int)(i % 576);
        int j = g >> 2, comp = g & 3;
        float v;
        if (comp == 0)      v = (k < 64) ? W_ih[j * 64 + k]          : W_hh[(long long)j * 512 + k - 64];
        else if (comp == 1) v = (k < 64) ? W_ih[(512 + j) * 64 + k]  : W_hh[(long long)(512 + j) * 512 + k - 64];
        else if (comp == 2) v = (k < 64) ? W_ih[(1024 + j) * 64 + k] : 0.f;
        else                v = (k < 64) ? 0.f                        : W_hh[(long long)(1024 + j) * 512 + k - 64];
        Wcat2[i] = v;
    }
    for (int i = t0; i < 2048; i += stride) {
        int j = i >> 2, comp = i & 3;
        float bv = (comp == 0) ? b_ih[j] + b_hh[j]
                 : (comp == 1) ? b_ih[512 + j] + b_hh[512 + j]
                 : (comp == 2) ? b_ih[1024 + j] : b_hh[1024 + j];
        bcat2[i] = bv;
    }
    if (t0 == 0) { done[0] = 0; done[8] = 0; }   // replay-safe counter reset
}

// ================= device helpers shared by merged & fallback =================

// A-part: argmax of step tprev for batch row b (one 256-thr block). smem regions passed in.
__device__ __forceinline__ int argmax_body(int b, int tprev,
    const float* __restrict__ tmaxv, const float* __restrict__ lprev,
    const float* __restrict__ hprev, const float* __restrict__ out_W,
    const float* __restrict__ out_b, float* __restrict__ seq, char* sm)
{
    float* s_red = (float*)sm;                 // 1024B
    int*   s_qt  = (int*)(sm + 1024);          // 256B
    int*   s_cand= (int*)(sm + 1280);          // 256B
    float* s_rv  = (float*)(sm + 1536);        // 256B
    int*   s_cnt = (int*)(sm + 1792);          // 8B
    int*   s_sym = (int*)(sm + 1800);          // 4B
    const int tid = threadIdx.x;
    const int lane = tid & 63, wave = tid >> 6;
    const float* row = lprev + (long long)b * (SLEN * (long long)VOCAB);

    float v0 = tmaxv[(long long)b * 512 + tid];
    float v1 = (tid + 256 < NTILE) ? tmaxv[(long long)b * 512 + 256 + tid] : -INFINITY;
    s_red[tid] = fmaxf(v0, v1); __syncthreads();
    for (int s = 128; s > 0; s >>= 1) {
        if (tid < s) s_red[tid] = fmaxf(s_red[tid], s_red[tid + s]);
        __syncthreads();
    }
    float M = s_red[0];
    if (tid == 0) { s_cnt[0] = 0; s_cnt[1] = 0; }
    __syncthreads();
    if (v0 >= M - MARGIN) {
        int s = atomicAdd(&s_cnt[0], 1);
        if (s < 64) s_qt[s] = tid;
    }
    if (v1 >= M - MARGIN) {
        int s = atomicAdd(&s_cnt[0], 1);
        if (s < 64) s_qt[s] = tid + 256;
    }
    __syncthreads();
    int nq = min(s_cnt[0], 64);
    for (int idx = tid; idx < nq * 64; idx += 256) {
        int c = s_qt[idx >> 6] * 64 + (idx & 63);
        if (row[c] >= M - MARGIN) {
            int s = atomicAdd(&s_cnt[1], 1);
            if (s < 64) s_cand[s] = c;
        }
    }
    __syncthreads();
    int nc = min(s_cnt[1], 64);
    const float* hrow = hprev + (long long)b * 512;
    for (int ci = wave; ci < nc; ci += 4) {
        int vv = s_cand[ci];
        const float* wrow = out_W + (long long)vv * 512;
        float s = 0.f;
        for (int k = lane; k < 512; k += 64) s = fmaf(hrow[k], wrow[k], s);
        for (int off = 32; off > 0; off >>= 1) s += __shfl_down(s, off, 64);
        if (lane == 0) s_rv[ci] = s + out_b[vv];
    }
    __syncthreads();
    if (tid == 0) {
        float bv = -INFINITY; int sym = 0x7fffffff;
        for (int ci = 0; ci < nc; ++ci) {
            float xx = s_rv[ci]; int c = s_cand[ci];
            if (xx > bv || (xx == bv && c < sym)) { bv = xx; sym = c; }
        }
        if (sym < 0 || sym >= VOCAB) sym = 0;   // crash-proofing
        seq[b * SLEN + tprev] = (float)sym;
        *s_sym = sym;
    }
    __syncthreads();
    return *s_sym;
}

// L-part: one 128x64 logits tile (R10-validated body). As at sm, Bs at sm+16384, s_mv at sm+24576.
__device__ __forceinline__ void logits_body(int bid,
    const ushort* __restrict__ hbf, const ushort* __restrict__ Wb,
    const float* __restrict__ out_b, float* __restrict__ lbase,
    float* __restrict__ tmaxv, char* sm)
{
    char* As = sm;
    char* Bs = sm + 16384;
    float* s_mv = (float*)(sm + 24576);
    const int tid = threadIdx.x;
    const int lane = tid & 63;
    const int wave = tid >> 6;
    const int job = (bid & 7) * 125 + (bid >> 3);
    const int jx = job >> 1;
    const int jy = job & 1;
    const int row0 = jy * 128;
    const int col0 = jx * 64;

    f32x4 acc[2][4] = {};
    const int srow = tid >> 3;
    const int sch = tid & 7;

    for (int k0 = 0; k0 < 512; k0 += 64) {
        #pragma unroll
        for (int ra = 0; ra < 4; ++ra) {
            int row = ra * 32 + srow;
            const char* g = (const char*)(hbf + (long long)(row0 + row) * 512 + k0) + ((sch ^ (row & 7)) * 16);
            __builtin_amdgcn_global_load_lds(
                (const __attribute__((address_space(1))) void*)g,
                (__attribute__((address_space(3))) void*)(As + row * 128 + sch * 16), 16, 0, 0);
        }
        #pragma unroll
        for (int rb = 0; rb < 2; ++rb) {
            int row = rb * 32 + srow;
            const char* g = (const char*)(Wb + (long long)(col0 + row) * 512 + k0) + ((sch ^ (row & 7)) * 16);
            __builtin_amdgcn_global_load_lds(
                (const __attribute__((address_space(1))) void*)g,
                (__attribute__((address_space(3))) void*)(Bs + row * 128 + sch * 16), 16, 0, 0);
        }
        __syncthreads();
        #pragma unroll
        for (int k32 = 0; k32 < 64; k32 += 32) {
            bf16x8 af[2], bfr[4];
            #pragma unroll
            for (int f = 0; f < 2; ++f) {
                int rA = wave * 32 + f * 16 + (lane & 15);
                int byteA = (rA * 128 + (k32 + ((lane >> 4) << 3)) * 2) ^ ((rA & 7) << 4);
                af[f] = *(const bf16x8*)&As[byteA];
            }
            #pragma unroll
            for (int j = 0; j < 4; ++j) {
                int rB = j * 16 + (lane & 15);
                int byteB = (rB * 128 + (k32 + ((lane >> 4) << 3)) * 2) ^ ((rB & 7) << 4);
                bfr[j] = *(const bf16x8*)&Bs[byteB];
            }
            #pragma unroll
            for (int f = 0; f < 2; ++f)
                #pragma unroll
                for (int j = 0; j < 4; ++j)
                    acc[f][j] = __builtin_amdgcn_mfma_f32_16x16x32_bf16(af[f], bfr[j], acc[f][j], 0, 0, 0);
        }
        __syncthreads();
    }

    #pragma unroll
    for (int f = 0; f < 2; ++f) {
        #pragma unroll
        for (int q = 0; q < 4; ++q) {
            int r_local = wave * 32 + f * 16 + ((lane >> 4) << 2) + q;
            float* crow = lbase + (long long)(row0 + r_local) * (SLEN * (long long)VOCAB);
            float mv = -INFINITY;
            #pragma unroll
            for (int j = 0; j < 4; ++j) {
                int c = col0 + j * 16 + (lane & 15);
                float v = acc[f][j][q] + out_b[c];
                __builtin_nontemporal_store(v, &crow[c]);
                mv = fmaxf(mv, v);
            }
            #pragma unroll
            for (int m = 1; m < 16; m <<= 1) mv = fmaxf(mv, __shfl_xor(mv, m, 64));
            if ((lane & 15) == 0) s_mv[r_local] = mv;
        }
    }
    __syncthreads();
    if (tid < 128)
        tmaxv[(long long)(row0 + tid) * 512 + jx] = s_mv[tid];
}

// G-part: gcat tile + gates. h-part first (K=64..575), e-part last. Writes hnew + packed hbfu.
// sm: As [64][18] at 0 (4608B), Bs [64][68] at 4608 (17408B), sh_hb at 8192 (512B, overlaps Bs
// only after its last use), gt reuses As region.
template<bool FIRST, bool MERGED>
__device__ __forceinline__ void gru_body(int blk,
    const float* __restrict__ hprev, float* __restrict__ hnew,
    const float* __restrict__ Wcat2, const float* __restrict__ bcat2,
    float* __restrict__ ebuf, const float* __restrict__ sos,
    unsigned* __restrict__ hbfu, int* __restrict__ done, int wt_e, char* sm)
{
    const int tid = threadIdx.x;
    const int ty = blk >> 5;            // 16-row batch group
    const int tx = blk & 31;            // col group (16 j x 4 comps)
    float* As = (float*)sm;                     // [64][18]
    float* Bs = (float*)(sm + 4608);            // [64][68]
    const int tyt = tid >> 4;
    const int txt = tid & 15;
    float acc[4] = {};

    // h-part: K = 64..575
    for (int k0 = 64; k0 < 576; k0 += 64) {
        for (int i = tid; i < 16 * 64; i += 256) {
            int m = i >> 6, k = i & 63;
            As[k * 18 + m] = hprev[(long long)(ty * 16 + m) * 512 + (k0 - 64) + k];
        }
        for (int i = tid; i < 64 * 64; i += 256) {
            int n = i >> 6, k = i & 63;
            Bs[k * 68 + n] = Wcat2[(long long)(tx * 64 + n) * 576 + k0 + k];
        }
        __syncthreads();
        #pragma unroll 8
        for (int kk = 0; kk < 64; ++kk) {
            const float a = As[kk * 18 + tyt];
            const float4 b = *(const float4*)&Bs[kk * 68 + txt * 4];
            acc[0] = fmaf(a, b.x, acc[0]);
            acc[1] = fmaf(a, b.y, acc[1]);
            acc[2] = fmaf(a, b.z, acc[2]);
            acc[3] = fmaf(a, b.w, acc[3]);
        }
        __syncthreads();
    }

    // wait for A-parts (overlapped by h-part), then e-part K=0..63
    if (!FIRST) {
        if (tid == 0) {
            while (__hip_atomic_load(&done[0], __ATOMIC_RELAXED, __HIP_MEMORY_SCOPE_AGENT) < wt_e)
                __builtin_amdgcn_s_sleep(8);
            __hip_atomic_load(&done[0], __ATOMIC_ACQUIRE, __HIP_MEMORY_SCOPE_AGENT);
        }
        __syncthreads();
    }
    {
        for (int i = tid; i < 16 * 64; i += 256) {
            int m = i >> 6, k = i & 63;
            float v;
            if (FIRST) v = sos[k];
            else v = __hip_atomic_load(&ebuf[(long long)(ty * 16 + m) * EMB + k],
                                       __ATOMIC_RELAXED, __HIP_MEMORY_SCOPE_AGENT);
            As[k * 18 + m] = v;
        }
        for (int i = tid; i < 64 * 64; i += 256) {
            int n = i >> 6, k = i & 63;
            Bs[k * 68 + n] = Wcat2[(long long)(tx * 64 + n) * 576 + k];
        }
        __syncthreads();
        #pragma unroll 8
        for (int kk = 0; kk < 64; ++kk) {
            const float a = As[kk * 18 + tyt];
            const float4 b = *(const float4*)&Bs[kk * 68 + txt * 4];
            acc[0] = fmaf(a, b.x, acc[0]);
            acc[1] = fmaf(a, b.y, acc[1]);
            acc[2] = fmaf(a, b.z, acc[2]);
            acc[3] = fmaf(a, b.w, acc[3]);
        }
        __syncthreads();
    }

    float* gt = (float*)sm;              // [16][64] reuse As region
    ushort* sh_hb = (ushort*)(sm + 8192);
    #pragma unroll
    for (int j = 0; j < 4; ++j)
        gt[tyt * 64 + txt * 4 + j] = acc[j];
    __syncthreads();
    {
        int row = tid >> 4, jl = tid & 15;
        int jg = tx * 16 + jl;
        float gr  = gt[row * 64 + jl * 4 + 0] + bcat2[jg * 4 + 0];
        float gz  = gt[row * 64 + jl * 4 + 1] + bcat2[jg * 4 + 1];
        float gni = gt[row * 64 + jl * 4 + 2] + bcat2[jg * 4 + 2];
        float gnh = gt[row * 64 + jl * 4 + 3] + bcat2[jg * 4 + 3];
        float r = 1.0f / (1.0f + expf(-gr));
        float z = 1.0f / (1.0f + expf(-gz));
        float n = tanhf(gni + r * gnh);
        long long bglob = ty * 16 + row;
        float hold = hprev[bglob * 512 + jg];
        float h = (1.0f - z) * n + z * hold;
        hnew[bglob * 512 + jg] = h;
        sh_hb[row * 16 + jl] = (ushort)bf16_rne(h);
    }
    __syncthreads();
    if (tid < 128) {
        int row = tid >> 3, jp = tid & 7;
        unsigned lo = sh_hb[row * 16 + jp * 2];
        unsigned hi = sh_hb[row * 16 + jp * 2 + 1];
        unsigned v = (hi << 16) | lo;
        long long idx = (long long)(ty * 16 + row) * 256 + tx * 8 + jp;
        if (MERGED)
            __hip_atomic_store(&hbfu[idx], v, __ATOMIC_RELAXED, __HIP_MEMORY_SCOPE_AGENT);
        else
            hbfu[idx] = v;
    }
    if (MERGED) {
        __syncthreads();
        if (tid == 0)
            __hip_atomic_fetch_add(&done[8], 1, __ATOMIC_RELEASE, __HIP_MEMORY_SCOPE_AGENT);
    }
}

// ================= merged kernel: A(t-1) + G(t) + L(t), 1000 blocks =================
template<bool FIRST>
__global__ __launch_bounds__(256) void gl_kernel(
    const float* __restrict__ hprev, float* __restrict__ hnew,
    const float* __restrict__ Wcat2, const float* __restrict__ bcat2,
    float* __restrict__ ebuf, const float* __restrict__ sos,
    unsigned* __restrict__ hbfu, const ushort* __restrict__ Wb,
    const float* __restrict__ out_W, const float* __restrict__ out_b,
    const float* __restrict__ emb, float* __restrict__ seq,
    float* __restrict__ tmaxv, const float* __restrict__ lprev,
    float* __restrict__ lbase, int* __restrict__ done,
    int wt_e, int wt_l, int tprev)
{
    __shared__ __align__(16) char smem[25600];
    const int tid = threadIdx.x;
    const int bid = blockIdx.x;

    // A-part: blocks 0..255 (skip at t=0)
    if (!FIRST && bid < BATCH) {
        int sym = argmax_body(bid, tprev, tmaxv, lprev, hprev, out_W, out_b, seq, smem);
        if (tid < EMB)
            __hip_atomic_store(&ebuf[(long long)bid * EMB + tid],
                               emb[(long long)sym * EMB + tid],
                               __ATOMIC_RELAXED, __HIP_MEMORY_SCOPE_AGENT);
        __syncthreads();
        if (tid == 0)
            __hip_atomic_fetch_add(&done[0], 1, __ATOMIC_RELEASE, __HIP_MEMORY_SCOPE_AGENT);
        __syncthreads();
    }

    // G-part: blocks 0..511
    if (bid < 512)
        gru_body<FIRST, true>(bid, hprev, hnew, Wcat2, bcat2, ebuf, sos, hbfu, done, wt_e, smem);

    // L-part: all 1000 blocks, after all G done
    if (tid == 0) {
        while (__hip_atomic_load(&done[8], __ATOMIC_RELAXED, __HIP_MEMORY_SCOPE_AGENT) < wt_l)
            __builtin_amdgcn_s_sleep(8);
        __hip_atomic_load(&done[8], __ATOMIC_ACQUIRE, __HIP_MEMORY_SCOPE_AGENT);
    }
    __syncthreads();
    logits_body(bid, (const ushort*)hbfu, Wb, out_b, lbase, tmaxv, smem);
}

// ================= fallback kernels (R14-validated two-node path) =================
template<bool FIRST>
__global__ __launch_bounds__(256) void ag2_kernel(
    const float* __restrict__ hprev, float* __restrict__ hnew,
    const float* __restrict__ Wcat2, const float* __restrict__ bcat2,
    float* __restrict__ ebuf, const float* __restrict__ sos,
    unsigned* __restrict__ hbfu,
    const float* __restrict__ tmaxv, const float* __restrict__ lprev,
    const float* __restrict__ out_W, const float* __restrict__ out_b,
    const float* __restrict__ emb, float* __restrict__ seq,
    int* __restrict__ done, int wt_e, int tprev)
{
    __shared__ __align__(16) char smem[25600];
    const int tid = threadIdx.x;
    const int bid = blockIdx.x;
    if (!FIRST && bid < BATCH) {
        int sym = argmax_body(bid, tprev, tmaxv, lprev, hprev, out_W, out_b, seq, smem);
        if (tid < EMB)
            __hip_atomic_store(&ebuf[(long long)bid * EMB + tid],
                               emb[(long long)sym * EMB + tid],
                               __ATOMIC_RELAXED, __HIP_MEMORY_SCOPE_AGENT);
        __syncthreads();
        if (tid == 0)
            __hip_atomic_fetch_add(&done[0], 1, __ATOMIC_RELEASE, __HIP_MEMORY_SCOPE_AGENT);
        __syncthreads();
    }
    gru_body<FIRST, false>(bid, hprev, hnew, Wcat2, bcat2, ebuf, sos, hbfu, done, wt_e, smem);
}

__global__ __launch_bounds__(256) void logits_bm128_kernel(
    const ushort* __restrict__ hbf, const ushort* __restrict__ Wb,
    const float* __restrict__ out_b,
    float* __restrict__ lbase, float* __restrict__ tmaxv)
{
    __shared__ __align__(16) char smem[25600];
    logits_body(blockIdx.x, hbf, Wb, out_b, lbase, tmaxv, smem);
}

// ---------- final argmax node for t = SLEN-1 ----------
__global__ __launch_bounds__(256) void argmax_final(
    const float* __restrict__ tmaxv, const float* __restrict__ lbase,
    const float* __restrict__ h, const float* __restrict__ out_W,
    const float* __restrict__ out_b, float* __restrict__ seq, int t)
{
    __shared__ __align__(16) char smem[2048];
    argmax_body(blockIdx.x, t, tmaxv, lbase, h, out_W, out_b, seq, smem);
}

extern "C" void kernel_launch(void* const* d_in, const int* in_sizes, int n_in,
                              void* d_out, int out_size, void* d_ws, size_t ws_size,
                              hipStream_t stream) {
    const float* x     = (const float*)d_in[0];
    const float* enc_W = (const float*)d_in[1];
    const float* enc_b = (const float*)d_in[2];
    const float* in_W  = (const float*)d_in[3];
    const float* in_b  = (const float*)d_in[4];
    const float* W_ih  = (const float*)d_in[5];
    const float* W_hh  = (const float*)d_in[6];
    const float* b_ih  = (const float*)d_in[7];
    const float* b_hh  = (const float*)d_in[8];
    const float* out_W = (const float*)d_in[9];
    const float* out_b = (const float*)d_in[10];
    const float* emb   = (const float*)d_in[11];
    const float* sos   = (const float*)d_in[12];

    float* seq    = (float*)d_out;
    float* logits = (float*)d_out + BATCH * SLEN;

    char* p = (char*)d_ws;
    ushort* Wb    = (ushort*)p;  p += (size_t)VOCAB * HSZ * 2;
    float* Wcat2  = (float*)p;   p += (size_t)2048 * 576 * 4;
    float* bcat2  = (float*)p;   p += 2048 * 4;
    float* hA     = (float*)p;   p += (size_t)BATCH * HSZ * 4;
    float* hB     = (float*)p;   p += (size_t)BATCH * HSZ * 4;
    unsigned* hbfu= (unsigned*)p; p += (size_t)BATCH * HSZ * 2;
    float* ebuf   = (float*)p;   p += (size_t)BATCH * EMB * 4;
    float* feat   = (float*)p;   p += (size_t)BATCH * DFEAT * 4;
    float* tmaxv  = (float*)p;   p += (size_t)BATCH * 512 * 4;
    int*   done   = (int*)p;     p += 64;

    // prologue
    prep_kernel<<<1024, 256, 0, stream>>>(out_W, Wb, W_ih, W_hh, b_ih, b_hh,
                                          Wcat2, bcat2, done);
    gemm_atb<64, 64, 32, 4, 4><<<dim3(DFEAT / 64, BATCH / 64), 256, 0, stream>>>(
        x, enc_W, enc_b, feat, DFEAT, BATCH, DFEAT, DIN);
    gemm_atb<64, 64, 32, 4, 4><<<dim3(HSZ / 64, BATCH / 64), 256, 0, stream>>>(
        feat, in_W, in_b, hA, HSZ, BATCH, HSZ, DFEAT);

    // co-residency check for the merged 1000-block kernel (deadlock-free condition)
    int nb = 0;
    hipError_t qerr = hipOccupancyMaxActiveBlocksPerMultiprocessor(
        &nb, reinterpret_cast<const void*>(gl_kernel<false>), 256, 0);
    bool merged = (qerr == hipSuccess && nb >= 4);   // 4/CU x 256 CU = 1024 >= 1000

    float* hc = hA;
    float* hn = hB;
    for (int t = 0; t < SLEN; ++t) {
        float* lbase = logits + (long long)t * VOCAB;
        const float* lprev = logits + (long long)(t > 0 ? t - 1 : 0) * VOCAB;
        if (merged) {
            if (t == 0) {
                gl_kernel<true><<<1000, 256, 0, stream>>>(
                    hc, hn, Wcat2, bcat2, ebuf, sos, hbfu, Wb, out_W, out_b, emb, seq,
                    tmaxv, lprev, lbase, done, 0, 512, 0);
            } else {
                gl_kernel<false><<<1000, 256, 0, stream>>>(
                    hc, hn, Wcat2, bcat2, ebuf, sos, hbfu, Wb, out_W, out_b, emb, seq,
                    tmaxv, lprev, lbase, done, 256 * t, 512 * (t + 1), t - 1);
            }
        } else {
            if (t == 0) {
                ag2_kernel<true><<<512, 256, 0, stream>>>(
                    hc, hn, Wcat2, bcat2, ebuf, sos, hbfu,
                    tmaxv, lprev, out_W, out_b, emb, seq, done, 0, 0);
            } else {
                ag2_kernel<false><<<512, 256, 0, stream>>>(
                    hc, hn, Wcat2, bcat2, ebuf, sos, hbfu,
                    tmaxv, lprev, out_W, out_b, emb, seq, done, 256 * t, t - 1);
            }
            logits_bm128_kernel<<<1000, 256, 0, stream>>>(
                (const ushort*)hbfu, Wb, out_b, lbase, tmaxv);
        }
        float* tmp = hc; hc = hn; hn = tmp;
    }
    // final argmax for t = 15 (final h is in hc after last swap)
    argmax_final<<<BATCH, 256, 0, stream>>>(
        tmaxv, logits + (long long)(SLEN - 1) * VOCAB, hc, out_W, out_b, seq, SLEN - 1);
}

// Round 16
// 1124.306 us; speedup vs baseline: 1.0274x; 1.0274x over previous
//
#include <hip/hip_runtime.h>
#include <math.h>

#define BATCH 256
#define DIN 512
#define DFEAT 512
#define HSZ 512
#define VOCAB 32000
#define EMB 64
#define SLEN 16
#define NTILE 500          // VOCAB / 64 col-tiles (argmax view)
#define MARGIN 0.0625f

typedef __attribute__((ext_vector_type(8))) short bf16x8;
typedef __attribute__((ext_vector_type(4))) float f32x4;

__device__ inline unsigned bf16_rne(float x) {
    union { float f; unsigned u; } u; u.f = x;
    unsigned r = u.u + 0x7fff + ((u.u >> 16) & 1);
    return r >> 16;
}

__device__ inline void poll_ge(int* c, int target) {
    while (__hip_atomic_load(c, __ATOMIC_RELAXED, __HIP_MEMORY_SCOPE_AGENT) < target)
        __builtin_amdgcn_s_sleep(8);
}
__device__ inline void bump(int* c) {
    __hip_atomic_fetch_add(c, 1, __ATOMIC_RELEASE, __HIP_MEMORY_SCOPE_AGENT);
}

// ---------- fp32 SMEM GEMM (prologue): C = A @ W^T (+bias) ----------
template<int BM, int BN, int BK, int TM, int TN>
__global__ __launch_bounds__(256) void gemm_atb(
    const float* __restrict__ A, const float* __restrict__ W,
    const float* __restrict__ bias, float* __restrict__ C, long long ldc,
    int M, int N, int K)
{
    __shared__ float As[BK][BM + 4];
    __shared__ float Bs[BK][BN + 4];
    constexpr int THREADS = (BM / TM) * (BN / TN);
    const int tid = threadIdx.x;
    const int tx = tid % (BN / TN);
    const int ty = tid / (BN / TN);
    const int row0 = blockIdx.y * BM;
    const int col0 = blockIdx.x * BN;
    float acc[TM][TN] = {};
    for (int k0 = 0; k0 < K; k0 += BK) {
        for (int i = tid; i < BM * BK; i += THREADS) {
            int m = i / BK, k = i % BK;
            As[k][m] = A[(long long)(row0 + m) * K + k0 + k];
        }
        for (int i = tid; i < BN * BK; i += THREADS) {
            int n = i / BK, k = i % BK;
            Bs[k][n] = W[(long long)(col0 + n) * K + k0 + k];
        }
        __syncthreads();
        #pragma unroll
        for (int kk = 0; kk < BK; ++kk) {
            float a[TM], b[TN];
            #pragma unroll
            for (int i = 0; i < TM; ++i) a[i] = As[kk][ty * TM + i];
            #pragma unroll
            for (int j = 0; j < TN; ++j) b[j] = Bs[kk][tx * TN + j];
            #pragma unroll
            for (int i = 0; i < TM; ++i)
                #pragma unroll
                for (int j = 0; j < TN; ++j)
                    acc[i][j] = fmaf(a[i], b[j], acc[i][j]);
        }
        __syncthreads();
    }
    #pragma unroll
    for (int i = 0; i < TM; ++i) {
        long long m = row0 + ty * TM + i;
        float* crow = C + m * ldc;
        #pragma unroll
        for (int j = 0; j < TN; ++j) {
            int n = col0 + tx * TN + j;
            float v = acc[i][j];
            if (bias) v += bias[n];
            crow[n] = v;
        }
    }
}

// ---------- prologue: Wb cast, Wcat2/bcat2 build, counter reset ----------
__global__ void prep_kernel(const float* __restrict__ out_W, ushort* __restrict__ Wb,
                            const float* __restrict__ W_ih, const float* __restrict__ W_hh,
                            const float* __restrict__ b_ih, const float* __restrict__ b_hh,
                            float* __restrict__ Wcat2, float* __restrict__ bcat2,
                            int* __restrict__ done)
{
    const int stride = gridDim.x * 256;
    const int t0 = blockIdx.x * 256 + threadIdx.x;
    for (int i = t0; i < VOCAB * HSZ / 4; i += stride) {
        const float4 v = ((const float4*)out_W)[i];
        ushort4 o;
        o.x = (ushort)bf16_rne(v.x); o.y = (ushort)bf16_rne(v.y);
        o.z = (ushort)bf16_rne(v.z); o.w = (ushort)bf16_rne(v.w);
        ((ushort4*)Wb)[i] = o;
    }
    for (long long i = t0; i < 2048LL * 576; i += stride) {
        int g = (int)(i / 576), k = (int)(i % 576);
        int j = g >> 2, comp = g & 3;
        float v;
        if (comp == 0)      v = (k < 64) ? W_ih[j * 64 + k]          : W_hh[(long long)j * 512 + k - 64];
        else if (comp == 1) v = (k < 64) ? W_ih[(512 + j) * 64 + k]  : W_hh[(long long)(512 + j) * 512 + k - 64];
        else if (comp == 2) v = (k < 64) ? W_ih[(1024 + j) * 64 + k] : 0.f;
        else                v = (k < 64) ? 0.f                        : W_hh[(long long)(1024 + j) * 512 + k - 64];
        Wcat2[i] = v;
    }
    for (int i = t0; i < 2048; i += stride) {
        int j = i >> 2, comp = i & 3;
        float bv = (comp == 0) ? b_ih[j] + b_hh[j]
                 : (comp == 1) ? b_ih[512 + j] + b_hh[512 + j]
                 : (comp == 2) ? b_ih[1024 + j] : b_hh[1024 + j];
        bcat2[i] = bv;
    }
    for (int i = t0; i < 256; i += stride) done[i] = 0;   // replay-safe reset
}

// ================= shared phase bodies =================

// A: argmax for row b of step tprev. Returns sym. (validated R10-R15)
__device__ __forceinline__ int argmax_body(int b, int tprev,
    const float* __restrict__ tmaxv, const float* __restrict__ lprev,
    const float* __restrict__ href, const float* __restrict__ out_W,
    const float* __restrict__ out_b, float* __restrict__ seq, char* sm)
{
    float* s_red = (float*)sm;
    int*   s_qt  = (int*)(sm + 1024);
    int*   s_cand= (int*)(sm + 1280);
    float* s_rv  = (float*)(sm + 1536);
    int*   s_cnt = (int*)(sm + 1792);
    int*   s_sym = (int*)(sm + 1800);
    const int tid = threadIdx.x;
    const int lane = tid & 63, wave = tid >> 6;
    const float* row = lprev + (long long)b * (SLEN * (long long)VOCAB);

    float v0 = tmaxv[(long long)b * 512 + tid];
    float v1 = (tid + 256 < NTILE) ? tmaxv[(long long)b * 512 + 256 + tid] : -INFINITY;
    s_red[tid] = fmaxf(v0, v1); __syncthreads();
    for (int s = 128; s > 0; s >>= 1) {
        if (tid < s) s_red[tid] = fmaxf(s_red[tid], s_red[tid + s]);
        __syncthreads();
    }
    float M = s_red[0];
    if (tid == 0) { s_cnt[0] = 0; s_cnt[1] = 0; }
    __syncthreads();
    if (v0 >= M - MARGIN) { int s = atomicAdd(&s_cnt[0], 1); if (s < 64) s_qt[s] = tid; }
    if (v1 >= M - MARGIN) { int s = atomicAdd(&s_cnt[0], 1); if (s < 64) s_qt[s] = tid + 256; }
    __syncthreads();
    int nq = min(s_cnt[0], 64);
    for (int idx = tid; idx < nq * 64; idx += 256) {
        int c = s_qt[idx >> 6] * 64 + (idx & 63);
        if (row[c] >= M - MARGIN) {
            int s = atomicAdd(&s_cnt[1], 1);
            if (s < 64) s_cand[s] = c;
        }
    }
    __syncthreads();
    int nc = min(s_cnt[1], 64);
    const float* hrow = href + (long long)b * 512;
    for (int ci = wave; ci < nc; ci += 4) {
        int vv = s_cand[ci];
        const float* wrow = out_W + (long long)vv * 512;
        float s = 0.f;
        for (int k = lane; k < 512; k += 64) s = fmaf(hrow[k], wrow[k], s);
        for (int off = 32; off > 0; off >>= 1) s += __shfl_down(s, off, 64);
        if (lane == 0) s_rv[ci] = s + out_b[vv];
    }
    __syncthreads();
    if (tid == 0) {
        float bv = -INFINITY; int sym = 0x7fffffff;
        for (int ci = 0; ci < nc; ++ci) {
            float xx = s_rv[ci]; int c = s_cand[ci];
            if (xx > bv || (xx == bv && c < sym)) { bv = xx; sym = c; }
        }
        if (sym < 0 || sym >= VOCAB) sym = 0;
        seq[b * SLEN + tprev] = (float)sym;
        *s_sym = sym;
    }
    __syncthreads();
    return *s_sym;
}

// G: gcat tile + gates for block blk. h-part first, e-part last. PERSIST => sc1 stores.
template<bool FIRST, bool PERSIST>
__device__ __forceinline__ void gru_body(int blk, int t,
    const float* __restrict__ hprev, float* __restrict__ hnew,
    const float* __restrict__ Wcat2, const float* __restrict__ bcat2,
    float* __restrict__ ebuf, const float* __restrict__ sos,
    unsigned* __restrict__ hbfu, int* __restrict__ done, int wt_e, char* sm)
{
    const int tid = threadIdx.x;
    const int ty = blk >> 5;
    const int tx = blk & 31;
    float* As = (float*)sm;                     // [64][18]
    float* Bs = (float*)(sm + 4608);            // [64][68]
    const int tyt = tid >> 4;
    const int txt = tid & 15;
    float acc[4] = {};

    if (PERSIST && !FIRST) {     // wait for h(t) rows of this half (written by G of step t-1)
        if (tid == 0) poll_ge(done + (t - 1) * 8 + 1 + (ty >= 8 ? 1 : 0), 256);
        __syncthreads();
    }
    for (int k0 = 64; k0 < 576; k0 += 64) {
        for (int i = tid; i < 16 * 64; i += 256) {
            int m = i >> 6, k = i & 63;
            As[k * 18 + m] = hprev[(long long)(ty * 16 + m) * 512 + (k0 - 64) + k];
        }
        for (int i = tid; i < 64 * 64; i += 256) {
            int n = i >> 6, k = i & 63;
            Bs[k * 68 + n] = Wcat2[(long long)(tx * 64 + n) * 576 + k0 + k];
        }
        __syncthreads();
        #pragma unroll 8
        for (int kk = 0; kk < 64; ++kk) {
            const float a = As[kk * 18 + tyt];
            const float4 b = *(const float4*)&Bs[kk * 68 + txt * 4];
            acc[0] = fmaf(a, b.x, acc[0]);
            acc[1] = fmaf(a, b.y, acc[1]);
            acc[2] = fmaf(a, b.z, acc[2]);
            acc[3] = fmaf(a, b.w, acc[3]);
        }
        __syncthreads();
    }

    if (!FIRST) {                 // wait for all A parts, then e-part
        if (tid == 0) poll_ge(done + (PERSIST ? t * 8 + 0 : 0), wt_e);
        __syncthreads();
    }
    {
        for (int i = tid; i < 16 * 64; i += 256) {
            int m = i >> 6, k = i & 63;
            float v;
            if (FIRST) v = sos[k];
            else v = ebuf[(long long)(ty * 16 + m) * EMB + k];
            As[k * 18 + m] = v;
        }
        for (int i = tid; i < 64 * 64; i += 256) {
            int n = i >> 6, k = i & 63;
            Bs[k * 68 + n] = Wcat2[(long long)(tx * 64 + n) * 576 + k];
        }
        __syncthreads();
        #pragma unroll 8
        for (int kk = 0; kk < 64; ++kk) {
            const float a = As[kk * 18 + tyt];
            const float4 b = *(const float4*)&Bs[kk * 68 + txt * 4];
            acc[0] = fmaf(a, b.x, acc[0]);
            acc[1] = fmaf(a, b.y, acc[1]);
            acc[2] = fmaf(a, b.z, acc[2]);
            acc[3] = fmaf(a, b.w, acc[3]);
        }
        __syncthreads();
    }

    float* gt = (float*)sm;
    ushort* sh_hb = (ushort*)(sm + 8192);
    #pragma unroll
    for (int j = 0; j < 4; ++j)
        gt[tyt * 64 + txt * 4 + j] = acc[j];
    __syncthreads();
    {
        int row = tid >> 4, jl = tid & 15;
        int jg = tx * 16 + jl;
        float gr  = gt[row * 64 + jl * 4 + 0] + bcat2[jg * 4 + 0];
        float gz  = gt[row * 64 + jl * 4 + 1] + bcat2[jg * 4 + 1];
        float gni = gt[row * 64 + jl * 4 + 2] + bcat2[jg * 4 + 2];
        float gnh = gt[row * 64 + jl * 4 + 3] + bcat2[jg * 4 + 3];
        float r = 1.0f / (1.0f + expf(-gr));
        float z = 1.0f / (1.0f + expf(-gz));
        float n = tanhf(gni + r * gnh);
        long long bglob = ty * 16 + row;
        float hold = hprev[bglob * 512 + jg];
        float h = (1.0f - z) * n + z * hold;
        if (PERSIST)
            __hip_atomic_store(&hnew[bglob * 512 + jg], h,
                               __ATOMIC_RELAXED, __HIP_MEMORY_SCOPE_AGENT);
        else
            hnew[bglob * 512 + jg] = h;
        sh_hb[row * 16 + jl] = (ushort)bf16_rne(h);
    }
    __syncthreads();
    if (tid < 128) {
        int row = tid >> 3, jp = tid & 7;
        unsigned lo = sh_hb[row * 16 + jp * 2];
        unsigned hi = sh_hb[row * 16 + jp * 2 + 1];
        unsigned v = (hi << 16) | lo;
        long long idx = (long long)(ty * 16 + row) * 256 + tx * 8 + jp;
        if (PERSIST)
            __hip_atomic_store(&hbfu[idx], v, __ATOMIC_RELAXED, __HIP_MEMORY_SCOPE_AGENT);
        else
            hbfu[idx] = v;
    }
    if (PERSIST) {
        __syncthreads();
        if (tid == 0) bump(done + t * 8 + 1 + (ty >= 8 ? 1 : 0));
    }
}

// L: one 128x64 logits tile (validated R10). PERSIST => sc1 stores.
template<bool PERSIST>
__device__ __forceinline__ void logits_body(int bid, int t,
    const ushort* __restrict__ hbf, const ushort* __restrict__ Wb,
    const float* __restrict__ out_b, float* __restrict__ lbase,
    float* __restrict__ tmaxv, int* __restrict__ done, char* sm)
{
    char* As = sm;
    char* Bs = sm + 16384;
    float* s_mv = (float*)(sm + 24576);
    const int tid = threadIdx.x;
    const int lane = tid & 63;
    const int wave = tid >> 6;
    const int job = (bid & 7) * 125 + (bid >> 3);
    const int jx = job >> 1;
    const int jy = job & 1;
    const int row0 = jy * 128;
    const int col0 = jx * 64;

    if (PERSIST) {               // wait for G half covering rows row0..row0+127
        if (tid == 0) poll_ge(done + t * 8 + 1 + jy, 256);
        __syncthreads();
    }

    f32x4 acc[2][4] = {};
    const int srow = tid >> 3;
    const int sch = tid & 7;

    for (int k0 = 0; k0 < 512; k0 += 64) {
        #pragma unroll
        for (int ra = 0; ra < 4; ++ra) {
            int row = ra * 32 + srow;
            const char* g = (const char*)(hbf + (long long)(row0 + row) * 512 + k0) + ((sch ^ (row & 7)) * 16);
            __builtin_amdgcn_global_load_lds(
                (const __attribute__((address_space(1))) void*)g,
                (__attribute__((address_space(3))) void*)(As + row * 128 + sch * 16), 16, 0, 0);
        }
        #pragma unroll
        for (int rb = 0; rb < 2; ++rb) {
            int row = rb * 32 + srow;
            const char* g = (const char*)(Wb + (long long)(col0 + row) * 512 + k0) + ((sch ^ (row & 7)) * 16);
            __builtin_amdgcn_global_load_lds(
                (const __attribute__((address_space(1))) void*)g,
                (__attribute__((address_space(3))) void*)(Bs + row * 128 + sch * 16), 16, 0, 0);
        }
        __syncthreads();
        #pragma unroll
        for (int k32 = 0; k32 < 64; k32 += 32) {
            bf16x8 af[2], bfr[4];
            #pragma unroll
            for (int f = 0; f < 2; ++f) {
                int rA = wave * 32 + f * 16 + (lane & 15);
                int byteA = (rA * 128 + (k32 + ((lane >> 4) << 3)) * 2) ^ ((rA & 7) << 4);
                af[f] = *(const bf16x8*)&As[byteA];
            }
            #pragma unroll
            for (int j = 0; j < 4; ++j) {
                int rB = j * 16 + (lane & 15);
                int byteB = (rB * 128 + (k32 + ((lane >> 4) << 3)) * 2) ^ ((rB & 7) << 4);
                bfr[j] = *(const bf16x8*)&Bs[byteB];
            }
            #pragma unroll
            for (int f = 0; f < 2; ++f)
                #pragma unroll
                for (int j = 0; j < 4; ++j)
                    acc[f][j] = __builtin_amdgcn_mfma_f32_16x16x32_bf16(af[f], bfr[j], acc[f][j], 0, 0, 0);
        }
        __syncthreads();
    }

    #pragma unroll
    for (int f = 0; f < 2; ++f) {
        #pragma unroll
        for (int q = 0; q < 4; ++q) {
            int r_local = wave * 32 + f * 16 + ((lane >> 4) << 2) + q;
            float* crow = lbase + (long long)(row0 + r_local) * (SLEN * (long long)VOCAB);
            float mv = -INFINITY;
            #pragma unroll
            for (int j = 0; j < 4; ++j) {
                int c = col0 + j * 16 + (lane & 15);
                float v = acc[f][j][q] + out_b[c];
                if (PERSIST)
                    __hip_atomic_store(&crow[c], v, __ATOMIC_RELAXED, __HIP_MEMORY_SCOPE_AGENT);
                else
                    __builtin_nontemporal_store(v, &crow[c]);
                mv = fmaxf(mv, v);
            }
            #pragma unroll
            for (int m = 1; m < 16; m <<= 1) mv = fmaxf(mv, __shfl_xor(mv, m, 64));
            if ((lane & 15) == 0) s_mv[r_local] = mv;
        }
    }
    __syncthreads();
    if (tid < 128) {
        float v = s_mv[tid];
        if (PERSIST)
            __hip_atomic_store(&tmaxv[(long long)(row0 + tid) * 512 + jx], v,
                               __ATOMIC_RELAXED, __HIP_MEMORY_SCOPE_AGENT);
        else
            tmaxv[(long long)(row0 + tid) * 512 + jx] = v;
    }
    if (PERSIST) {
        __syncthreads();
        if (tid == 0) bump(done + t * 8 + 3 + jy);
    }
}

// ================= persistent kernel: all 16 steps =================
__global__ __launch_bounds__(256) void persist_kernel(
    float* __restrict__ hbase,          // h[t] = hbase + t*B*H, t=0..16
    const float* __restrict__ Wcat2, const float* __restrict__ bcat2,
    float* __restrict__ ebase,          // ebuf[t] = ebase + t*B*E
    const float* __restrict__ sos,
    unsigned* __restrict__ hbase_u,     // hbfu[t] = hbase_u + t*B*H/2 (u32 units: B*256)
    const ushort* __restrict__ Wb,
    const float* __restrict__ out_W, const float* __restrict__ out_b,
    const float* __restrict__ emb, float* __restrict__ seq,
    float* __restrict__ tmbase,         // tmaxv[t] = tmbase + t*B*512
    float* __restrict__ logits,         // [B][SLEN][V]
    int* __restrict__ done)
{
    __shared__ __align__(16) char smem[25600];
    const int tid = threadIdx.x;
    const int bid = blockIdx.x;

    for (int t = 0; t <= SLEN; ++t) {
        // ---- A phase: argmax of step t-1 (blocks 0..255) ----
        if (t > 0 && bid < BATCH) {
            const int half = (bid >= 128) ? 1 : 0;
            if (tid == 0) poll_ge(done + (t - 1) * 8 + 3 + half, 500);
            __syncthreads();
            int sym = argmax_body(bid, t - 1,
                                  tmbase + (long long)(t - 1) * BATCH * 512,
                                  logits + (long long)(t - 1) * VOCAB,
                                  hbase + (long long)t * BATCH * HSZ,
                                  out_W, out_b, seq, smem);
            if (t < SLEN) {
                if (tid < EMB)
                    __hip_atomic_store(&ebase[(long long)t * BATCH * EMB + (long long)bid * EMB + tid],
                                       emb[(long long)sym * EMB + tid],
                                       __ATOMIC_RELAXED, __HIP_MEMORY_SCOPE_AGENT);
                __syncthreads();
                if (tid == 0) bump(done + t * 8 + 0);
            }
            __syncthreads();
        }
        if (t == SLEN) break;

        // ---- G phase (blocks 0..511) ----
        if (bid < 512) {
            if (t == 0)
                gru_body<true, true>(bid, t,
                    hbase, hbase + (long long)BATCH * HSZ,
                    Wcat2, bcat2, ebase, sos,
                    hbase_u, done, 0, smem);
            else
                gru_body<false, true>(bid, t,
                    hbase + (long long)t * BATCH * HSZ,
                    hbase + (long long)(t + 1) * BATCH * HSZ,
                    Wcat2, bcat2,
                    ebase + (long long)t * BATCH * EMB, sos,
                    hbase_u + (long long)t * BATCH * 256, done, 256, smem);
        }

        // ---- L phase (all 1000 blocks) ----
        logits_body<true>(bid, t,
            (const ushort*)(hbase_u + (long long)t * BATCH * 256), Wb, out_b,
            logits + (long long)t * VOCAB,
            tmbase + (long long)t * BATCH * 512, done, smem);
    }
}

// ================= fallback kernels (R14-validated two-node path) =================
template<bool FIRST>
__global__ __launch_bounds__(256) void ag2_kernel(
    const float* __restrict__ hprev, float* __restrict__ hnew,
    const float* __restrict__ Wcat2, const float* __restrict__ bcat2,
    float* __restrict__ ebuf, const float* __restrict__ sos,
    unsigned* __restrict__ hbfu,
    const float* __restrict__ tmaxv, const float* __restrict__ lprev,
    const float* __restrict__ out_W, const float* __restrict__ out_b,
    const float* __restrict__ emb, float* __restrict__ seq,
    int* __restrict__ done, int wt_e, int tprev)
{
    __shared__ __align__(16) char smem[25600];
    const int tid = threadIdx.x;
    const int bid = blockIdx.x;
    if (!FIRST && bid < BATCH) {
        int sym = argmax_body(bid, tprev, tmaxv, lprev, hprev, out_W, out_b, seq, smem);
        if (tid < EMB)
            __hip_atomic_store(&ebuf[(long long)bid * EMB + tid],
                               emb[(long long)sym * EMB + tid],
                               __ATOMIC_RELAXED, __HIP_MEMORY_SCOPE_AGENT);
        __syncthreads();
        if (tid == 0) bump(done);
        __syncthreads();
    }
    gru_body<FIRST, false>(bid, 0, hprev, hnew, Wcat2, bcat2, ebuf, sos, hbfu, done, wt_e, smem);
}

__global__ __launch_bounds__(256) void logits_bm128_kernel(
    const ushort* __restrict__ hbf, const ushort* __restrict__ Wb,
    const float* __restrict__ out_b,
    float* __restrict__ lbase, float* __restrict__ tmaxv)
{
    __shared__ __align__(16) char smem[25600];
    logits_body<false>(blockIdx.x, 0, hbf, Wb, out_b, lbase, tmaxv, nullptr, smem);
}

__global__ __launch_bounds__(256) void argmax_final(
    const float* __restrict__ tmaxv, const float* __restrict__ lbase,
    const float* __restrict__ h, const float* __restrict__ out_W,
    const float* __restrict__ out_b, float* __restrict__ seq, int t)
{
    __shared__ __align__(16) char smem[2048];
    argmax_body(blockIdx.x, t, tmaxv, lbase, h, out_W, out_b, seq, smem);
}

extern "C" void kernel_launch(void* const* d_in, const int* in_sizes, int n_in,
                              void* d_out, int out_size, void* d_ws, size_t ws_size,
                              hipStream_t stream) {
    const float* x     = (const float*)d_in[0];
    const float* enc_W = (const float*)d_in[1];
    const float* enc_b = (const float*)d_in[2];
    const float* in_W  = (const float*)d_in[3];
    const float* in_b  = (const float*)d_in[4];
    const float* W_ih  = (const float*)d_in[5];
    const float* W_hh  = (const float*)d_in[6];
    const float* b_ih  = (const float*)d_in[7];
    const float* b_hh  = (const float*)d_in[8];
    const float* out_W = (const float*)d_in[9];
    const float* out_b = (const float*)d_in[10];
    const float* emb   = (const float*)d_in[11];
    const float* sos   = (const float*)d_in[12];

    float* seq    = (float*)d_out;
    float* logits = (float*)d_out + BATCH * SLEN;

    // layout: shared prefix (fallback-compatible), then persistent extras
    char* p = (char*)d_ws;
    ushort* Wb    = (ushort*)p;   p += (size_t)VOCAB * HSZ * 2;
    float* Wcat2  = (float*)p;    p += (size_t)2048 * 576 * 4;
    float* bcat2  = (float*)p;    p += 2048 * 4;
    float* feat   = (float*)p;    p += (size_t)BATCH * DFEAT * 4;
    int*   done   = (int*)p;      p += 1024;
    float* hbase  = (float*)p;    p += (size_t)2 * BATCH * HSZ * 4;   // fallback: h[0],h[1]
    unsigned* hbu = (unsigned*)p; p += (size_t)BATCH * HSZ * 2;       // fallback hbfu[0]
    float* ebase  = (float*)p;    p += (size_t)BATCH * EMB * 4;       // fallback ebuf[0]
    float* tmbase = (float*)p;    p += (size_t)BATCH * 512 * 4;       // fallback tmaxv[0]
    size_t base_need = (size_t)(p - (char*)d_ws);

    // persistent needs the full per-step arrays
    size_t persist_need = (size_t)VOCAB * HSZ * 2 + 2048LL * 576 * 4 + 2048 * 4
        + (size_t)BATCH * DFEAT * 4 + 1024
        + 17LL * BATCH * HSZ * 4          // h[0..16]
        + 16LL * BATCH * HSZ * 2          // hbfu[0..15]
        + 16LL * BATCH * EMB * 4          // ebuf[0..15]
        + 16LL * BATCH * 512 * 4;         // tmaxv[0..15]

    int nb = 0;
    hipError_t qerr = hipOccupancyMaxActiveBlocksPerMultiprocessor(
        &nb, reinterpret_cast<const void*>(persist_kernel), 256, 0);
    bool persist = (qerr == hipSuccess) && (nb >= 4) && (ws_size >= persist_need);

    if (persist) {
        // re-lay out with full arrays
        char* q = (char*)d_ws;
        Wb    = (ushort*)q;   q += (size_t)VOCAB * HSZ * 2;
        Wcat2 = (float*)q;    q += (size_t)2048 * 576 * 4;
        bcat2 = (float*)q;    q += 2048 * 4;
        feat  = (float*)q;    q += (size_t)BATCH * DFEAT * 4;
        done  = (int*)q;      q += 1024;
        hbase = (float*)q;    q += 17LL * BATCH * HSZ * 4;
        hbu   = (unsigned*)q; q += 16LL * BATCH * HSZ * 2;
        ebase = (float*)q;    q += 16LL * BATCH * EMB * 4;
        tmbase= (float*)q;    q += 16LL * BATCH * 512 * 4;
    }
    (void)base_need;

    // prologue
    prep_kernel<<<1024, 256, 0, stream>>>(out_W, Wb, W_ih, W_hh, b_ih, b_hh,
                                          Wcat2, bcat2, done);
    gemm_atb<64, 64, 32, 4, 4><<<dim3(DFEAT / 64, BATCH / 64), 256, 0, stream>>>(
        x, enc_W, enc_b, feat, DFEAT, BATCH, DFEAT, DIN);
    gemm_atb<64, 64, 32, 4, 4><<<dim3(HSZ / 64, BATCH / 64), 256, 0, stream>>>(
        feat, in_W, in_b, hbase, HSZ, BATCH, HSZ, DFEAT);   // h[0]

    if (persist) {
        persist_kernel<<<1000, 256, 0, stream>>>(
            hbase, Wcat2, bcat2, ebase, sos, hbu, Wb,
            out_W, out_b, emb, seq, tmbase, logits, done);
    } else {
        float* hc = hbase;                       // h[0]
        float* hn = hbase + (size_t)BATCH * HSZ; // h[1]
        for (int t = 0; t < SLEN; ++t) {
            float* lbase = logits + (long long)t * VOCAB;
            const float* lprev = logits + (long long)(t > 0 ? t - 1 : 0) * VOCAB;
            if (t == 0) {
                ag2_kernel<true><<<512, 256, 0, stream>>>(
                    hc, hn, Wcat2, bcat2, ebase, sos, hbu,
                    tmbase, lprev, out_W, out_b, emb, seq, done, 0, 0);
            } else {
                ag2_kernel<false><<<512, 256, 0, stream>>>(
                    hc, hn, Wcat2, bcat2, ebase, sos, hbu,
                    tmbase, lprev, out_W, out_b, emb, seq, done, 256 * t, t - 1);
            }
            logits_bm128_kernel<<<1000, 256, 0, stream>>>(
                (const ushort*)hbu, Wb, out_b, lbase, tmbase);
            float* tmp = hc; hc = hn; hn = tmp;
        }
        argmax_final<<<BATCH, 256, 0, stream>>>(
            tmbase, logits + (long long)(SLEN - 1) * VOCAB, hc, out_W, out_b, seq, SLEN - 1);
    }
}